// Round 1
// baseline (1863.605 us; speedup 1.0000x reference)
//
#include <hip/hip_runtime.h>
#include <hip/hip_bf16.h>

typedef __attribute__((ext_vector_type(8))) short short8;
typedef __attribute__((ext_vector_type(4))) float f32x4;
typedef unsigned short ushort_t;

// Problem constants
#define BB 512     // batch
#define HH 1024    // hidden
#define DD 96      // io dim (3*NB)
#define TT 25      // decoder steps
// Wc: 6144 gate rows (64 hb16-groups * 6 gates * 16) + 96 out rows
#define NWC 6240

__device__ __forceinline__ float sigm(float x){ return 1.f/(1.f+__expf(-x)); }
__device__ __forceinline__ float tanh_(float x){
  float e = __expf(-2.f*fabsf(x));
  float t = (1.f-e)/(1.f+e);
  return copysignf(t, x);
}
// round-to-nearest-even f32 -> bf16
__device__ __forceinline__ ushort_t f2bf(float x){
  union { float f; unsigned u; } v; v.f = x;
  unsigned r = v.u + 0x7FFFu + ((v.u>>16)&1u);
  return (ushort_t)(r>>16);
}

// row layout of Wc: for hidden col j (0..1023): hb16=j>>4, u=j&15
//   gate g (0..5): row = hb16*96 + g*16 + u   (g 0-2 = gi-path (Wx), 3-5 = gh-path (Whh))
//   out d (0..95): row = 6144 + d             (Wc[6144+d][k] = W_out[k][d])

// ---- prep 1: cast Whh into Wc (gh rows), W_out^T into Wc (out rows); cbias for those rows
__global__ void k_prep_cast(const float* __restrict__ Whh, const float* __restrict__ bhh,
                            const float* __restrict__ Wout, const float* __restrict__ bout,
                            ushort_t* __restrict__ Wc, float* __restrict__ cbias){
  int bid = blockIdx.x, tid = threadIdx.x;
  if (bid < 3072){
    int g = bid >> 10, j = bid & 1023;
    int dest = (j>>4)*96 + (3+g)*16 + (j&15);
    const float* src = Whh + (size_t)bid*1024;
    ushort_t* dst = Wc + (size_t)dest*1024;
    for (int k = tid; k < 1024; k += 256) dst[k] = f2bf(src[k]);
    if (!tid) cbias[dest] = bhh[bid];
  } else {
    int d = bid - 3072;
    int dest = 6144 + d;
    ushort_t* dst = Wc + (size_t)dest*1024;
    for (int k = tid; k < 1024; k += 256) dst[k] = f2bf(Wout[(size_t)k*96 + d]);
    if (!tid) cbias[dest] = bout[d];
  }
}

// ---- prep 2: Wx[n][k] = sum_d Wih[n][d]*Wout[k][d]  (fold of out-projection into gi path)
__global__ void k_prep_wx(const float* __restrict__ Wih, const float* __restrict__ Wout,
                          ushort_t* __restrict__ Wc){
  __shared__ float sWih[32][97];
  __shared__ float sWo[64][97];
  int tid = threadIdx.x;
  int nt = blockIdx.x % 96, kt = blockIdx.x / 96;   // n-tile of 32, k-tile of 64
  for (int i = tid; i < 32*96; i += 256){ int r=i/96, d=i%96; sWih[r][d] = Wih[(size_t)(nt*32+r)*96 + d]; }
  for (int i = tid; i < 64*96; i += 256){ int r=i/96, d=i%96; sWo[r][d]  = Wout[(size_t)(kt*64+r)*96 + d]; }
  __syncthreads();
  int ni = tid & 31;
  int kb = tid >> 5;   // 0..7
  float acc[8];
  #pragma unroll
  for (int i=0;i<8;i++) acc[i]=0.f;
  for (int d = 0; d < 96; d++){
    float a = sWih[ni][d];
    #pragma unroll
    for (int i=0;i<8;i++) acc[i] += a * sWo[kb + i*8][d];
  }
  int n = nt*32 + ni;
  int g = n >> 10, j = n & 1023;
  int dest = (j>>4)*96 + g*16 + (j&15);
  ushort_t* dst = Wc + (size_t)dest*1024 + kt*64;
  #pragma unroll
  for (int i=0;i<8;i++) dst[kb + i*8] = f2bf(acc[i]);
}

// ---- prep 3: cbias for gi rows: bih[n] + sum_d bout[d]*Wih[n][d]
__global__ void k_prep_cx(const float* __restrict__ Wih, const float* __restrict__ bih,
                          const float* __restrict__ bout, float* __restrict__ cbias){
  int n = blockIdx.x*256 + threadIdx.x;
  if (n >= 3072) return;
  float acc = bih[n];
  const float* wrow = Wih + (size_t)n*96;
  for (int d = 0; d < 96; d++) acc += bout[d]*wrow[d];
  int g = n >> 10, j = n & 1023;
  int dest = (j>>4)*96 + g*16 + (j&15);
  cbias[dest] = acc;
}

// ---- step 0: h1 = gru(p, 0) in fp32.  gh = bhh exactly (h=0).
__global__ void k_step0(const float* __restrict__ dec_in, const float* __restrict__ Wih,
                        const float* __restrict__ bih, const float* __restrict__ bhh,
                        float* __restrict__ h_f32, ushort_t* __restrict__ h_bf){
  __shared__ float sP[64][97];
  __shared__ float sW[64][97];
  int tid = threadIdx.x;
  int bt = blockIdx.x & 7;     // batch tile (64 rows)
  int jt = blockIdx.x >> 3;    // hidden tile (64 cols), 16 tiles
  for (int i = tid; i < 64*96; i += 256){ int r=i/96, d=i%96; sP[r][d] = dec_in[(size_t)(bt*64+r)*96 + d]; }
  int tb = tid >> 4, tj = tid & 15;     // 16x16 thread grid, each does 4x4
  float gg[3][4][4];
  for (int g = 0; g < 3; g++){
    __syncthreads();
    for (int i = tid; i < 64*96; i += 256){ int r=i/96, d=i%96; sW[r][d] = Wih[((size_t)g*1024 + jt*64 + r)*96 + d]; }
    __syncthreads();
    float acc[4][4];
    #pragma unroll
    for (int x=0;x<4;x++)
      #pragma unroll
      for (int y=0;y<4;y++) acc[x][y]=0.f;
    for (int d = 0; d < 96; d++){
      float a[4], wv[4];
      #pragma unroll
      for (int x=0;x<4;x++) a[x]  = sP[tb + x*16][d];
      #pragma unroll
      for (int y=0;y<4;y++) wv[y] = sW[tj + y*16][d];
      #pragma unroll
      for (int x=0;x<4;x++)
        #pragma unroll
        for (int y=0;y<4;y++) acc[x][y] += a[x]*wv[y];
    }
    #pragma unroll
    for (int x=0;x<4;x++)
      #pragma unroll
      for (int y=0;y<4;y++) gg[g][x][y] = acc[x][y];
  }
  #pragma unroll
  for (int x=0;x<4;x++)
    #pragma unroll
    for (int y=0;y<4;y++){
      int b = bt*64 + tb + x*16;
      int j = jt*64 + tj + y*16;
      float gir = gg[0][x][y] + bih[j];
      float giz = gg[1][x][y] + bih[1024+j];
      float gin = gg[2][x][y] + bih[2048+j];
      float r = sigm(gir + bhh[j]);
      float z = sigm(giz + bhh[1024+j]);
      float nn = tanh_(gin + r*bhh[2048+j]);
      float h = (1.f - z)*nn;
      h_f32[(size_t)b*1024 + j] = h;
      h_bf [(size_t)b*1024 + j] = f2bf(h);
    }
}

// ---- main step: C = h @ Wc^T (N=6240, K=1024) + gates + out write, one launch per step
template<bool IS_OUT>
__device__ __forceinline__ void step_core(int bid, int tid,
    const ushort_t* __restrict__ h_in_bf, const float* __restrict__ h_in_f32,
    const ushort_t* __restrict__ Wc, const float* __restrict__ cbias,
    float* __restrict__ h_out_f32, ushort_t* __restrict__ h_out_bf,
    float* __restrict__ pred, int tm1){
  int lane = tid & 63, w = tid >> 6;
  int l16 = lane & 15, lk = lane >> 4;
  int row0, col0;
  if (IS_OUT){ row0 = (bid - 256)*128 + w*32; col0 = 6144; }
  else {
    int rt = bid & 7, hbp = bid >> 3;
    int wr = w >> 1, wc = w & 1;
    row0 = rt*64 + wr*32;
    col0 = (hbp*2 + wc)*96;
  }
  const short8* Ap = (const short8*)h_in_bf + (size_t)(row0 + l16)*128 + lk;
  const short8* Bp = (const short8*)Wc      + (size_t)(col0 + l16)*128 + lk;
  f32x4 acc[2][6];
  #pragma unroll
  for (int m=0;m<2;m++)
    #pragma unroll
    for (int n=0;n<6;n++) acc[m][n] = f32x4{0.f,0.f,0.f,0.f};
  for (int k0 = 0; k0 < 1024; k0 += 32){
    short8 a0 = Ap[0];
    short8 a1 = Ap[2048];     // +16 rows
    #pragma unroll
    for (int n = 0; n < 6; n++){
      short8 b = Bp[n*2048];
      acc[0][n] = __builtin_amdgcn_mfma_f32_16x16x32_bf16(a0, b, acc[0][n], 0,0,0);
      acc[1][n] = __builtin_amdgcn_mfma_f32_16x16x32_bf16(a1, b, acc[1][n], 0,0,0);
    }
    Ap += 4; Bp += 4;         // advance 32 k-elements
  }
  if (IS_OUT){
    #pragma unroll
    for (int n=0;n<6;n++){
      int c = n*16 + l16;
      float bias = cbias[6144 + c];
      #pragma unroll
      for (int m=0;m<2;m++)
        #pragma unroll
        for (int j=0;j<4;j++){
          int bg = row0 + m*16 + lk*4 + j;
          pred[(size_t)bg*2400 + tm1*96 + c] = acc[m][n][j] + bias;
        }
    }
  } else {
    int hb16 = col0 / 96;
    int jg = hb16*16 + l16;
    float c0 = cbias[col0 +  0 + l16];
    float c1 = cbias[col0 + 16 + l16];
    float c2 = cbias[col0 + 32 + l16];
    float c3 = cbias[col0 + 48 + l16];
    float c4 = cbias[col0 + 64 + l16];
    float c5 = cbias[col0 + 80 + l16];
    #pragma unroll
    for (int m=0;m<2;m++){
      #pragma unroll
      for (int j=0;j<4;j++){
        int bg = row0 + m*16 + lk*4 + j;
        float gir = acc[m][0][j] + c0;
        float giz = acc[m][1][j] + c1;
        float gin = acc[m][2][j] + c2;
        float ghr = acc[m][3][j] + c3;
        float ghz = acc[m][4][j] + c4;
        float ghn = acc[m][5][j] + c5;
        float r  = sigm(gir + ghr);
        float z  = sigm(giz + ghz);
        float nn = tanh_(gin + r*ghn);
        float hold = h_in_f32[(size_t)bg*1024 + jg];
        float hnew = (1.f - z)*nn + z*hold;
        h_out_f32[(size_t)bg*1024 + jg] = hnew;
        h_out_bf [(size_t)bg*1024 + jg] = f2bf(hnew);
      }
    }
  }
}

__global__ __launch_bounds__(256)
void k_step(const ushort_t* __restrict__ h_in_bf, const float* __restrict__ h_in_f32,
            const ushort_t* __restrict__ Wc, const float* __restrict__ cbias,
            float* __restrict__ h_out_f32, ushort_t* __restrict__ h_out_bf,
            float* __restrict__ pred, int tm1){
  if (blockIdx.x < 256)
    step_core<false>(blockIdx.x, threadIdx.x, h_in_bf, h_in_f32, Wc, cbias, h_out_f32, h_out_bf, pred, tm1);
  else
    step_core<true >(blockIdx.x, threadIdx.x, h_in_bf, h_in_f32, Wc, cbias, h_out_f32, h_out_bf, pred, tm1);
}

extern "C" void kernel_launch(void* const* d_in, const int* in_sizes, int n_in,
                              void* d_out, int out_size, void* d_ws, size_t ws_size,
                              hipStream_t stream){
  // inputs: 0 enc_in, 1 dec_in, 2..5 enc_*, 6 dec_Wih, 7 dec_Whh, 8 dec_bih,
  //         9 dec_bhh, 10 W_out, 11 b_out.  Encoder is DEAD CODE in the reference.
  const float* dec_in = (const float*)d_in[1];
  const float* Wih  = (const float*)d_in[6];
  const float* Whh  = (const float*)d_in[7];
  const float* bih  = (const float*)d_in[8];
  const float* bhh  = (const float*)d_in[9];
  const float* Wout = (const float*)d_in[10];
  const float* bout = (const float*)d_in[11];
  float* pred = (float*)d_out;   // [512][25][96] fp32

  char* ws = (char*)d_ws;
  size_t off = 0;
  ushort_t* Wc = (ushort_t*)(ws + off); off += (size_t)NWC*1024*2;       // 12.19 MiB bf16
  float* cbias = (float*)(ws + off);    off += (size_t)NWC*4;
  off = (off + 255) & ~(size_t)255;
  float* hA = (float*)(ws + off);       off += (size_t)BB*HH*4;
  float* hB = (float*)(ws + off);       off += (size_t)BB*HH*4;
  ushort_t* hbA = (ushort_t*)(ws + off); off += (size_t)BB*HH*2;
  ushort_t* hbB = (ushort_t*)(ws + off); off += (size_t)BB*HH*2;

  k_prep_cast<<<3168, 256, 0, stream>>>(Whh, bhh, Wout, bout, Wc, cbias);
  k_prep_wx  <<<1536, 256, 0, stream>>>(Wih, Wout, Wc);
  k_prep_cx  <<<12,   256, 0, stream>>>(Wih, bih, bout, cbias);
  k_step0    <<<128,  256, 0, stream>>>(dec_in, Wih, bih, bhh, hA, hbA);

  float*    hf[2] = {hA, hB};
  ushort_t* hb[2] = {hbA, hbB};
  for (int t = 1; t <= TT; t++){
    int ci = (t-1)&1, ni = t&1;
    k_step<<<260, 256, 0, stream>>>(hb[ci], hf[ci], Wc, cbias, hf[ni], hb[ni], pred, t-1);
  }
}

// Round 2
// 700.198 us; speedup vs baseline: 2.6615x; 2.6615x over previous
//
#include <hip/hip_runtime.h>
#include <hip/hip_bf16.h>

typedef __attribute__((ext_vector_type(8))) short short8;
typedef __attribute__((ext_vector_type(4))) float f32x4;
typedef unsigned short u16;

// Problem constants
#define BB 512     // batch
#define HH 1024    // hidden
#define TT 25      // decoder steps
#define CTB 128    // ct blocks (each owns 8 hidden cols -> 48 Wc rows)

__device__ __forceinline__ float sigm(float x){ return 1.f/(1.f+__expf(-x)); }
__device__ __forceinline__ float tanh_(float x){
  float e = __expf(-2.f*fabsf(x));
  float t = (1.f-e)/(1.f+e);
  return copysignf(t, x);
}
__device__ __forceinline__ u16 f2bf(float x){
  union { float f; unsigned u; } v; v.f = x;
  unsigned r = v.u + 0x7FFFu + ((v.u>>16)&1u);
  return (u16)(r>>16);
}

// Wcp layout: per ct block (8 hidden cols), 48 rows (r = gate*8 + u, gates:
// 0=gir 1=giz 2=gin 3=ghr 4=ghz 5=ghn), pre-packed in MFMA B-frag order:
// elem idx = ct*49152 + ((kit*3 + nf)*64 + lane)*8 + e
// where nf=r>>4, lane=(r&15) | ((k31>>3)<<4), kit=k>>5, e=k&7.
__device__ __forceinline__ size_t wc_idx(int ct, int r, int k){
  int nf = r>>4, rl = r&15, kit = k>>5, k31 = k&31;
  int lane = rl | (((k31>>3)&3)<<4);
  return (size_t)ct*49152 + ((size_t)(kit*3+nf)*64 + (size_t)lane)*8 + (k31&7);
}

// ---- prep 1: Whh -> Wcp gate rows 3..5 (+cbias), Wout -> WoT (bf16 [96][1024])
__global__ void k_prep_cast(const float* __restrict__ Whh, const float* __restrict__ bhh,
                            const float* __restrict__ Wout,
                            u16* __restrict__ Wcp, float* __restrict__ cbias,
                            u16* __restrict__ WoT){
  int bid = blockIdx.x, tid = threadIdx.x;
  if (bid < 3072){
    int g1 = bid >> 10, j = bid & 1023;
    int ct = j >> 3, u = j & 7, r = (3+g1)*8 + u;
    const float* src = Whh + (size_t)bid*1024;
    if (tid < 128){
      int k0 = tid*8;
      size_t base = wc_idx(ct, r, k0);
      #pragma unroll
      for (int i=0;i<8;i++) Wcp[base+i] = f2bf(src[k0+i]);
    }
    if (!tid) cbias[ct*48 + r] = bhh[bid];
  } else {
    int d = bid - 3072;
    for (int k = tid; k < 1024; k += 256)
      WoT[(size_t)d*1024 + k] = f2bf(Wout[(size_t)k*96 + d]);
  }
}

// ---- prep 2: Wx[n][k] = sum_d Wih[n][d]*Wout[k][d]  (out-proj folded into gi path)
__global__ void k_prep_wx(const float* __restrict__ Wih, const float* __restrict__ Wout,
                          u16* __restrict__ Wcp){
  __shared__ float sWih[32][97];
  __shared__ float sWo[64][97];
  int tid = threadIdx.x;
  int nt = blockIdx.x % 96, kt = blockIdx.x / 96;   // n-tile 32, k-tile 64
  for (int i = tid; i < 32*96; i += 256){ int r2=i/96, d=i%96; sWih[r2][d] = Wih[(size_t)(nt*32+r2)*96 + d]; }
  for (int i = tid; i < 64*96; i += 256){ int r2=i/96, d=i%96; sWo[r2][d]  = Wout[(size_t)(kt*64+r2)*96 + d]; }
  __syncthreads();
  int ni = tid & 31, kb = tid >> 5;    // thread owns 8 consecutive k
  float acc[8];
  #pragma unroll
  for (int i=0;i<8;i++) acc[i]=0.f;
  for (int d = 0; d < 96; d++){
    float a = sWih[ni][d];
    #pragma unroll
    for (int i=0;i<8;i++) acc[i] += a * sWo[kb*8 + i][d];
  }
  int n = nt*32 + ni;
  int g = n >> 10, j = n & 1023;
  int ct = j >> 3, u = j & 7, r = g*8 + u;
  size_t base = wc_idx(ct, r, kt*64 + kb*8);
  #pragma unroll
  for (int i=0;i<8;i++) Wcp[base+i] = f2bf(acc[i]);
}

// ---- prep 3: cbias gi rows: bih[n] + sum_d bout[d]*Wih[n][d]
__global__ void k_prep_cx(const float* __restrict__ Wih, const float* __restrict__ bih,
                          const float* __restrict__ bout, float* __restrict__ cbias){
  int n = blockIdx.x*256 + threadIdx.x;
  if (n >= 3072) return;
  float acc = bih[n];
  const float* wrow = Wih + (size_t)n*96;
  for (int d = 0; d < 96; d++) acc += bout[d]*wrow[d];
  int g = n >> 10, j = n & 1023;
  cbias[(j>>3)*48 + g*8 + (j&7)] = acc;
}

// ---- step 0: h1 = gru(p, 0) in fp32 (gh = bhh exactly since h=0)
__global__ void k_step0(const float* __restrict__ dec_in, const float* __restrict__ Wih,
                        const float* __restrict__ bih, const float* __restrict__ bhh,
                        float* __restrict__ h_f32, u16* __restrict__ h_bf){
  __shared__ float sP[64][97];
  __shared__ float sW[64][97];
  int tid = threadIdx.x;
  int bt = blockIdx.x & 7;
  int jt = blockIdx.x >> 3;
  for (int i = tid; i < 64*96; i += 256){ int r=i/96, d=i%96; sP[r][d] = dec_in[(size_t)(bt*64+r)*96 + d]; }
  int tb = tid >> 4, tj = tid & 15;
  float gg[3][4][4];
  for (int g = 0; g < 3; g++){
    __syncthreads();
    for (int i = tid; i < 64*96; i += 256){ int r=i/96, d=i%96; sW[r][d] = Wih[((size_t)g*1024 + jt*64 + r)*96 + d]; }
    __syncthreads();
    float acc[4][4];
    #pragma unroll
    for (int x=0;x<4;x++)
      #pragma unroll
      for (int y=0;y<4;y++) acc[x][y]=0.f;
    for (int d = 0; d < 96; d++){
      float a[4], wv[4];
      #pragma unroll
      for (int x=0;x<4;x++) a[x]  = sP[tb + x*16][d];
      #pragma unroll
      for (int y=0;y<4;y++) wv[y] = sW[tj + y*16][d];
      #pragma unroll
      for (int x=0;x<4;x++)
        #pragma unroll
        for (int y=0;y<4;y++) acc[x][y] += a[x]*wv[y];
    }
    #pragma unroll
    for (int x=0;x<4;x++)
      #pragma unroll
      for (int y=0;y<4;y++) gg[g][x][y] = acc[x][y];
  }
  #pragma unroll
  for (int x=0;x<4;x++)
    #pragma unroll
    for (int y=0;y<4;y++){
      int b = bt*64 + tb + x*16;
      int j = jt*64 + tj + y*16;
      float gir = gg[0][x][y] + bih[j];
      float giz = gg[1][x][y] + bih[1024+j];
      float gin = gg[2][x][y] + bih[2048+j];
      float r = sigm(gir + bhh[j]);
      float z = sigm(giz + bhh[1024+j]);
      float nn = tanh_(gin + r*bhh[2048+j]);
      float h = (1.f - z)*nn;
      h_f32[(size_t)b*1024 + j] = h;
      h_bf [(size_t)b*1024 + j] = f2bf(h);
    }
}

// ---- main step: LDS-resident Wc slice; 256 blocks x 512 thr; tile 256 batch x 48 rows.
// Also computes pred[t-1] = h_t @ Wout + bout (blocks 0..191) fused.
__global__ __launch_bounds__(512)
void k_step2(const u16* __restrict__ hin_bf, const float* __restrict__ hin_f32,
             const u16* __restrict__ Wcp, const float* __restrict__ cbias,
             const u16* __restrict__ WoT, const float* __restrict__ bout,
             float* __restrict__ hout_f32, u16* __restrict__ hout_bf,
             float* __restrict__ pred, int tm1, int do_recur){
  __shared__ short8 sB[6144];       // 96 KB: Wc slice in B-frag order
  __shared__ f32x4 sPred[8][64];    // 8 KB: pred split-K partials
  int b = blockIdx.x, tid = threadIdx.x;
  int lane = tid & 63, w = tid >> 6;          // 8 waves
  int l16 = lane & 15, lk = lane >> 4;
  // XCD-aware mapping: blocks on one XCD share a batch half
  int r8 = b & 7;
  int bt = r8 >> 2;
  int ct = (b >> 3)*4 + (r8 & 3);             // ct in [0,128)

  if (do_recur){
    const short8* Wblk = (const short8*)Wcp + (size_t)ct*6144;
    for (int i = tid; i < 6144; i += 512) sB[i] = Wblk[i];
  }

  // ---- fused out-projection for h_t (tm1 = t-1): blocks 0..191 = 32 bm x 6 bn
  if (b < 192){
    int bm = b/6, bn = b%6;
    const short8* Aq = (const short8*)hin_bf + (size_t)(bm*16 + l16)*128 + lk + (size_t)w*16;
    const short8* Bq = (const short8*)WoT   + (size_t)(bn*16 + l16)*128 + lk + (size_t)w*16;
    f32x4 accp = {0.f,0.f,0.f,0.f};
    #pragma unroll
    for (int kit = 0; kit < 4; kit++)
      accp = __builtin_amdgcn_mfma_f32_16x16x32_bf16(Aq[kit*4], Bq[kit*4], accp, 0,0,0);
    sPred[w][lane] = accp;
  }
  __syncthreads();
  if (b < 192 && w == 0){
    f32x4 s = sPred[0][lane];
    #pragma unroll
    for (int ww=1; ww<8; ww++) s += sPred[ww][lane];
    int bm = b/6, bn = b%6;
    int c = bn*16 + l16;
    float bb = bout[c];
    #pragma unroll
    for (int j=0;j<4;j++){
      int row = bm*16 + lk*4 + j;
      pred[(size_t)row*2400 + (size_t)tm1*96 + c] = s[j] + bb;
    }
  }
  if (!do_recur) return;

  // ---- recurrence: C = h_t[bt-half] @ WcSlice^T, gates, h_{t+1}
  int rowA = bt*256 + w*32;                    // wave owns 32 batch rows
  const short8* Ap = (const short8*)hin_bf + (size_t)(rowA + l16)*128 + lk;
  f32x4 acc[2][3];
  #pragma unroll
  for (int m=0;m<2;m++)
    #pragma unroll
    for (int nf=0;nf<3;nf++) acc[m][nf] = f32x4{0.f,0.f,0.f,0.f};
  #pragma unroll 4
  for (int kit = 0; kit < 32; kit++){
    short8 a0 = Ap[0];
    short8 a1 = Ap[2048];                      // +16 batch rows
    const short8* Bs = &sB[kit*192 + lane];
    #pragma unroll
    for (int nf = 0; nf < 3; nf++){
      short8 bv = Bs[nf*64];
      acc[0][nf] = __builtin_amdgcn_mfma_f32_16x16x32_bf16(a0, bv, acc[0][nf], 0,0,0);
      acc[1][nf] = __builtin_amdgcn_mfma_f32_16x16x32_bf16(a1, bv, acc[1][nf], 0,0,0);
    }
    Ap += 4;
  }

  // gate math: lane pair (l, l^8): lo lane has gir,gin,ghz; hi lane giz,ghr,ghn
  float c0 = cbias[ct*48 +  0 + l16];
  float c1 = cbias[ct*48 + 16 + l16];
  float c2 = cbias[ct*48 + 32 + l16];
  bool hiB = (l16 & 8) != 0;
  int colg = ct*8 + (l16 & 7);
  #pragma unroll
  for (int mf=0; mf<2; mf++){
    #pragma unroll
    for (int j=0;j<4;j++){
      int batch = rowA + mf*16 + lk*4 + j;
      float a0 = acc[mf][0][j] + c0;   // lo: gir   hi: giz
      float a1 = acc[mf][1][j] + c1;   // lo: gin   hi: ghr
      float a2 = acc[mf][2][j] + c2;   // lo: ghz   hi: ghn
      float v1 = hiB ? a1 : a2;                 // hi sends ghr, lo sends ghz
      float w1 = __shfl_xor(v1, 8, 64);
      float rz = sigm(a0 + w1);                 // lo: r = sigm(gir+ghr), hi: z = sigm(giz+ghz)
      float w2 = __shfl_xor(rz, 8, 64);         // lo gets z, hi gets r
      float v3 = hiB ? (w2 * a2) : 0.f;         // hi: r*ghn
      float w3 = __shfl_xor(v3, 8, 64);         // lo gets r*ghn
      if (!hiB){
        float nn = tanh_(a1 + w3);              // tanh(gin + r*ghn)
        float z  = w2;
        float hold = hin_f32[(size_t)batch*1024 + colg];
        float hnew = (1.f - z)*nn + z*hold;
        hout_f32[(size_t)batch*1024 + colg] = hnew;
        hout_bf [(size_t)batch*1024 + colg] = f2bf(hnew);
      }
    }
  }
}

extern "C" void kernel_launch(void* const* d_in, const int* in_sizes, int n_in,
                              void* d_out, int out_size, void* d_ws, size_t ws_size,
                              hipStream_t stream){
  // inputs: 0 enc_in, 1 dec_in, 2..5 enc_* (DEAD CODE), 6 dec_Wih, 7 dec_Whh,
  //         8 dec_bih, 9 dec_bhh, 10 W_out, 11 b_out
  const float* dec_in = (const float*)d_in[1];
  const float* Wih  = (const float*)d_in[6];
  const float* Whh  = (const float*)d_in[7];
  const float* bih  = (const float*)d_in[8];
  const float* bhh  = (const float*)d_in[9];
  const float* Wout = (const float*)d_in[10];
  const float* bout = (const float*)d_in[11];
  float* pred = (float*)d_out;   // [512][25][96] fp32

  char* ws = (char*)d_ws;
  size_t off = 0;
  u16* Wcp = (u16*)(ws + off);   off += (size_t)CTB*48*1024*2;     // 12.58 MB
  u16* WoT = (u16*)(ws + off);   off += (size_t)96*1024*2;         // 196 KB
  float* cbias = (float*)(ws + off); off += (size_t)6144*4;
  off = (off + 255) & ~(size_t)255;
  float* hfA = (float*)(ws + off); off += (size_t)BB*HH*4;
  float* hfB = (float*)(ws + off); off += (size_t)BB*HH*4;
  u16* hbA = (u16*)(ws + off);     off += (size_t)BB*HH*2;
  u16* hbB = (u16*)(ws + off);     off += (size_t)BB*HH*2;

  k_prep_cast<<<3168, 256, 0, stream>>>(Whh, bhh, Wout, Wcp, cbias, WoT);
  k_prep_wx  <<<1536, 256, 0, stream>>>(Wih, Wout, Wcp);
  k_prep_cx  <<<12,   256, 0, stream>>>(Wih, bih, bout, cbias);
  k_step0    <<<128,  256, 0, stream>>>(dec_in, Wih, bih, bhh, hfA, hbA);

  float* hf[2] = {hfA, hfB};
  u16*   hb[2] = {hbA, hbB};
  // steps t=1..24: compute h_{t+1} AND pred[t-1] from h_t
  for (int t = 1; t <= 24; t++){
    int ci = (t-1)&1, ni = t&1;
    k_step2<<<256, 512, 0, stream>>>(hb[ci], hf[ci], Wcp, cbias, WoT, bout,
                                     hf[ni], hb[ni], pred, t-1, 1);
  }
  // final: pred[24] from h_25 (in buffer A), no recurrence
  k_step2<<<256, 512, 0, stream>>>(hb[0], hf[0], Wcp, cbias, WoT, bout,
                                   hf[1], hb[1], pred, 24, 0);
}